// Round 1
// baseline (422.198 us; speedup 1.0000x reference)
//
#include <hip/hip_runtime.h>
#include <math.h>

// Problem constants (fixed by reference setup_inputs)
#define T_TOK 16384   // B*S = 4*4096
#define DDIM  2048
#define NE    64      // experts == wave size
#define TPB   32      // tokens per block
#define DK    64      // K tile
#define WPAD  68      // padded leading dim for W tile (conflict-free b128)

// Output layout in d_out (float):
//   [0 .. 32767]      expert_indices as float, token-major, k-minor
//   [32768 .. 65535]  expert_weights
//   [65536]           aux_loss

__global__ __launch_bounds__(256, 2)
void router_main(const float* __restrict__ x, const float* __restrict__ W,
                 float* __restrict__ out, double* __restrict__ usage) {
    __shared__ float xs[TPB][DK];     // 8 KB, broadcast-read
    __shared__ float wsh[NE][WPAD];   // 17.4 KB, padded for b128 reads

    const int tid  = threadIdx.x;
    const int lane = tid & 63;        // expert id
    const int wv   = tid >> 6;        // wave id 0..3 -> token subgroup
    const int t0   = blockIdx.x * TPB;

    // 4 interleaved fp32 accumulation chains per token (low rounding error)
    float4 acc[8];
#pragma unroll
    for (int j = 0; j < 8; ++j) acc[j] = make_float4(0.f, 0.f, 0.f, 0.f);

    for (int kt = 0; kt < DDIM / DK; ++kt) {
        const int kbase = kt * DK;
        // stage x tile: 32 rows x 16 float4
#pragma unroll
        for (int i = 0; i < 2; ++i) {
            int idx = tid + i * 256;          // 0..511
            int row = idx >> 4;
            int c4  = idx & 15;
            float4 v = *(const float4*)&x[(size_t)(t0 + row) * DDIM + kbase + c4 * 4];
            *(float4*)&xs[row][c4 * 4] = v;
        }
        // stage W tile: 64 rows x 16 float4
#pragma unroll
        for (int i = 0; i < 4; ++i) {
            int idx = tid + i * 256;          // 0..1023
            int row = idx >> 4;
            int c4  = idx & 15;
            float4 v = *(const float4*)&W[(size_t)row * DDIM + kbase + c4 * 4];
            *(float4*)&wsh[row][c4 * 4] = v;
        }
        __syncthreads();

#pragma unroll
        for (int c4 = 0; c4 < 16; ++c4) {
            float4 w4 = *(const float4*)&wsh[lane][c4 * 4];   // per-expert row
#pragma unroll
            for (int j = 0; j < 8; ++j) {
                float4 x4 = *(const float4*)&xs[wv * 8 + j][c4 * 4];  // broadcast
                acc[j].x = fmaf(x4.x, w4.x, acc[j].x);
                acc[j].y = fmaf(x4.y, w4.y, acc[j].y);
                acc[j].z = fmaf(x4.z, w4.z, acc[j].z);
                acc[j].w = fmaf(x4.w, w4.w, acc[j].w);
            }
        }
        __syncthreads();
    }

    // ---- epilogue: softmax / top-2 / usage, one wave per 8 tokens ----
    float usage_acc = 0.f;
#pragma unroll
    for (int j = 0; j < 8; ++j) {
        const int t = t0 + wv * 8 + j;
        float l = (acc[j].x + acc[j].y) + (acc[j].z + acc[j].w);

        // top-1 (argmax, tie -> lower index, matching jax.lax.top_k)
        float v1 = l; int i1 = lane;
#pragma unroll
        for (int off = 32; off >= 1; off >>= 1) {
            float ov = __shfl_xor(v1, off, 64);
            int   oi = __shfl_xor(i1, off, 64);
            if (ov > v1 || (ov == v1 && oi < i1)) { v1 = ov; i1 = oi; }
        }
        // top-2
        float lm = (lane == i1) ? -INFINITY : l;
        float v2 = lm; int i2 = lane;
#pragma unroll
        for (int off = 32; off >= 1; off >>= 1) {
            float ov = __shfl_xor(v2, off, 64);
            int   oi = __shfl_xor(i2, off, 64);
            if (ov > v2 || (ov == v2 && oi < i2)) { v2 = ov; i2 = oi; }
        }

        // softmax denom (full, for usage) + top-2 weights
        float p = expf(l - v1);
        float s = p;
#pragma unroll
        for (int off = 32; off >= 1; off >>= 1) s += __shfl_xor(s, off, 64);

        float e2  = expf(v2 - v1);
        float rcp = 1.0f / (1.0f + e2);
        float w1  = rcp;
        float w2  = e2 * rcp;

        usage_acc += p / s;

        if (lane == 0) {
            out[(size_t)t * 2 + 0]          = (float)i1;
            out[(size_t)t * 2 + 1]          = (float)i2;
            out[32768 + (size_t)t * 2 + 0]  = w1;
            out[32768 + (size_t)t * 2 + 1]  = w2;
        }
    }

    // per-expert usage: one fp64 atomic per wave (deterministic to fp32)
    atomicAdd(&usage[lane], (double)usage_acc);
}

__global__ void router_aux(const double* __restrict__ usage, float* __restrict__ out) {
    int lane = threadIdx.x;  // 64 threads
    double u  = usage[lane] * (1.0 / 16384.0) - (1.0 / 64.0);
    double sq = u * u;
#pragma unroll
    for (int off = 32; off >= 1; off >>= 1) sq += __shfl_xor(sq, off, 64);
    if (lane == 0) out[65536] = (float)sq;
}

extern "C" void kernel_launch(void* const* d_in, const int* in_sizes, int n_in,
                              void* d_out, int out_size, void* d_ws, size_t ws_size,
                              hipStream_t stream) {
    const float* x = (const float*)d_in[0];   // [4,4096,2048] fp32
    const float* W = (const float*)d_in[1];   // [64,2048] fp32
    float* out     = (float*)d_out;           // 65537 floats
    double* usage  = (double*)d_ws;           // 64 doubles of scratch

    hipMemsetAsync(usage, 0, NE * sizeof(double), stream);
    router_main<<<dim3(T_TOK / TPB), dim3(256), 0, stream>>>(x, W, out, usage);
    router_aux<<<dim3(1), dim3(64), 0, stream>>>(usage, out);
}